// Round 3
// baseline (138.853 us; speedup 1.0000x reference)
//
#include <hip/hip_runtime.h>
#include <math.h>

#define NB   16
#define NH   128
#define NW   128
#define NCLS 80
#define NPOS (NB * NH * NW)          // 262144 spatial positions
#define STRIDE_F 8.0f

#define BLOCKS_A (NPOS / 256)        // 1024: bbox decode, 1 thread/pos
#define BLOCKS_B (NPOS / 64)         // 4096: cls reduce, 4 lanes/pos, 64 pos/block

// Native vector type for __builtin_nontemporal_load (HIP's float4 is a class,
// which the builtin rejects; clang ext_vector_type is accepted).
typedef float f32x4 __attribute__((ext_vector_type(4)));

// Output layout (flat, reference return order):
//   [0 .. 4*NPOS)        xywh, float4 per position
//   [4*NPOS .. 5*NPOS)   argmax class index (as float)
//   [5*NPOS .. 6*NPOS)   conf = sqrt(sigmoid(center)*sigmoid(max_logit))
__global__ __launch_bounds__(256) void fcos_decode_kernel(
    const float* __restrict__ bbox,
    const float* __restrict__ center,
    const float* __restrict__ cls,
    float* __restrict__ out)
{
    const int bid = blockIdx.x;

    if (bid < BLOCKS_A) {
        // ---------- Role A: bbox ltrb->xywh, fully coalesced ----------
        const int pos = bid * 256 + threadIdx.x;
        const int w = pos & (NW - 1);
        const int h = (pos >> 7) & (NH - 1);

        // Zero-reuse stream: nt hint keeps these lines evict-first in L2 so
        // they don't fight the concurrent fill-writeback / cls stream.
        const f32x4 ltrb = __builtin_nontemporal_load((const f32x4*)bbox + pos);
        const float l = expf(ltrb.x) * STRIDE_F;
        const float t = expf(ltrb.y) * STRIDE_F;
        const float r = expf(ltrb.z) * STRIDE_F;
        const float b = expf(ltrb.w) * STRIDE_F;

        const float cx = (float)w * STRIDE_F + STRIDE_F * 0.5f;
        const float cy = (float)h * STRIDE_F + STRIDE_F * 0.5f;

        ((float4*)out)[pos] = make_float4(cx - (l - r) * 0.5f,
                                          cy - (t - b) * 0.5f,
                                          l + r,
                                          t + b);
    } else {
        // ---------- Role B: class max/argmax + centerness conf ----------
        // 4 lanes per position; lane q covers classes [q*20, q*20+20).
        const int b    = bid - BLOCKS_A;
        const int wave = threadIdx.x >> 6;
        const int lane = threadIdx.x & 63;
        const int p    = lane >> 2;          // 0..15 position within wave
        const int q    = lane & 3;           // 0..3 class chunk
        const int pos  = b * 64 + wave * 16 + p;

        // 80 B per lane, 5 KB contiguous per wave — every line fully used.
        // nt: 84 MB single-pass stream, keep it out of L2 residency.
        const f32x4* cp = (const f32x4*)(cls + (size_t)pos * NCLS + q * 20);
        const f32x4 v0 = __builtin_nontemporal_load(cp + 0);
        const f32x4 v1 = __builtin_nontemporal_load(cp + 1);
        const f32x4 v2 = __builtin_nontemporal_load(cp + 2);
        const f32x4 v3 = __builtin_nontemporal_load(cp + 3);
        const f32x4 v4 = __builtin_nontemporal_load(cp + 4);

        // Issue the center load NOW so its HBM latency hides under the
        // 20-compare scan chain instead of serializing at the wave tail.
        float cen = 0.0f;
        if (q == 0) cen = center[pos];

        float best = v0.x; int li = 0;
        #define SCAN(val, j) if ((val) > best) { best = (val); li = (j); }
        SCAN(v0.y, 1)  SCAN(v0.z, 2)  SCAN(v0.w, 3)
        SCAN(v1.x, 4)  SCAN(v1.y, 5)  SCAN(v1.z, 6)  SCAN(v1.w, 7)
        SCAN(v2.x, 8)  SCAN(v2.y, 9)  SCAN(v2.z, 10) SCAN(v2.w, 11)
        SCAN(v3.x, 12) SCAN(v3.y, 13) SCAN(v3.z, 14) SCAN(v3.w, 15)
        SCAN(v4.x, 16) SCAN(v4.y, 17) SCAN(v4.z, 18) SCAN(v4.w, 19)
        #undef SCAN
        int idx = q * 20 + li;

        // Butterfly over the 4-lane group; first-occurrence tie-break.
        #pragma unroll
        for (int mask = 1; mask <= 2; mask <<= 1) {
            const float ov = __shfl_xor(best, mask);
            const int   oi = __shfl_xor(idx,  mask);
            if (ov > best || (ov == best && oi < idx)) { best = ov; idx = oi; }
        }

        if (q == 0) {
            // 16 active lanes read/write 64 contiguous bytes each — coalesced.
            const float sc   = 1.0f / (1.0f + expf(-cen));
            const float ss   = 1.0f / (1.0f + expf(-best));
            out[(size_t)4 * NPOS + pos] = (float)idx;
            out[(size_t)5 * NPOS + pos] = sqrtf(sc * ss);
        }
    }
}

extern "C" void kernel_launch(void* const* d_in, const int* in_sizes, int n_in,
                              void* d_out, int out_size, void* d_ws, size_t ws_size,
                              hipStream_t stream)
{
    const float* bbox   = (const float*)d_in[0];
    const float* center = (const float*)d_in[1];
    const float* cls    = (const float*)d_in[2];
    float* out = (float*)d_out;

    fcos_decode_kernel<<<BLOCKS_A + BLOCKS_B, 256, 0, stream>>>(bbox, center, cls, out);
}

// Round 4
// 126.257 us; speedup vs baseline: 1.0998x; 1.0998x over previous
//
#include <hip/hip_runtime.h>
#include <math.h>

#define NB   16
#define NH   128
#define NW   128
#define NCLS 80
#define NPOS (NB * NH * NW)          // 262144 spatial positions
#define STRIDE_F 8.0f

#define BLOCKS_A (NPOS / 256)        // 1024: bbox decode, 1 thread/pos
#define BLOCKS_B (NPOS / 64)         // 4096: cls reduce, 4 lanes/pos, 64 pos/block

// Output layout (flat, reference return order):
//   [0 .. 4*NPOS)        xywh, float4 per position
//   [4*NPOS .. 5*NPOS)   argmax class index (as float)
//   [5*NPOS .. 6*NPOS)   conf = sqrt(sigmoid(center)*sigmoid(max_logit))
//
// NOTE (R3 lesson): do NOT use __builtin_nontemporal_load on the cls stream.
// Adjacent lanes share 64-B lines (80-B stride); nt bypasses cache allocation
// on gfx950 and re-fetches shared lines from HBM (+13 us measured).
__global__ __launch_bounds__(256) void fcos_decode_kernel(
    const float* __restrict__ bbox,
    const float* __restrict__ center,
    const float* __restrict__ cls,
    float* __restrict__ out)
{
    const int bid = blockIdx.x;

    if (bid < BLOCKS_A) {
        // ---------- Role A: bbox ltrb->xywh, fully coalesced ----------
        const int pos = bid * 256 + threadIdx.x;
        const int w = pos & (NW - 1);
        const int h = (pos >> 7) & (NH - 1);

        const float4 ltrb = ((const float4*)bbox)[pos];
        const float l = expf(ltrb.x) * STRIDE_F;
        const float t = expf(ltrb.y) * STRIDE_F;
        const float r = expf(ltrb.z) * STRIDE_F;
        const float b = expf(ltrb.w) * STRIDE_F;

        const float cx = (float)w * STRIDE_F + STRIDE_F * 0.5f;
        const float cy = (float)h * STRIDE_F + STRIDE_F * 0.5f;

        ((float4*)out)[pos] = make_float4(cx - (l - r) * 0.5f,
                                          cy - (t - b) * 0.5f,
                                          l + r,
                                          t + b);
    } else {
        // ---------- Role B: class max/argmax + centerness conf ----------
        // 4 lanes per position; lane q covers classes [q*20, q*20+20).
        const int b    = bid - BLOCKS_A;
        const int wave = threadIdx.x >> 6;
        const int lane = threadIdx.x & 63;
        const int p    = lane >> 2;          // 0..15 position within wave
        const int q    = lane & 3;           // 0..3 class chunk
        const int pos  = b * 64 + wave * 16 + p;

        // 80 B per lane, 5 KB contiguous per wave — every line fully used.
        const float4* cp = (const float4*)(cls + (size_t)pos * NCLS + q * 20);
        const float4 v0 = cp[0];
        const float4 v1 = cp[1];
        const float4 v2 = cp[2];
        const float4 v3 = cp[3];
        const float4 v4 = cp[4];

        // Issue the center load early so its HBM latency hides under the
        // 20-compare scan chain instead of serializing at the wave tail.
        float cen = 0.0f;
        if (q == 0) cen = center[pos];

        float best = v0.x; int li = 0;
        #define SCAN(val, j) if ((val) > best) { best = (val); li = (j); }
        SCAN(v0.y, 1)  SCAN(v0.z, 2)  SCAN(v0.w, 3)
        SCAN(v1.x, 4)  SCAN(v1.y, 5)  SCAN(v1.z, 6)  SCAN(v1.w, 7)
        SCAN(v2.x, 8)  SCAN(v2.y, 9)  SCAN(v2.z, 10) SCAN(v2.w, 11)
        SCAN(v3.x, 12) SCAN(v3.y, 13) SCAN(v3.z, 14) SCAN(v3.w, 15)
        SCAN(v4.x, 16) SCAN(v4.y, 17) SCAN(v4.z, 18) SCAN(v4.w, 19)
        #undef SCAN
        int idx = q * 20 + li;

        // Butterfly over the 4-lane group; first-occurrence tie-break.
        #pragma unroll
        for (int mask = 1; mask <= 2; mask <<= 1) {
            const float ov = __shfl_xor(best, mask);
            const int   oi = __shfl_xor(idx,  mask);
            if (ov > best || (ov == best && oi < idx)) { best = ov; idx = oi; }
        }

        if (q == 0) {
            // 16 active lanes read/write 64 contiguous bytes each — coalesced.
            const float sc   = 1.0f / (1.0f + expf(-cen));
            const float ss   = 1.0f / (1.0f + expf(-best));
            out[(size_t)4 * NPOS + pos] = (float)idx;
            out[(size_t)5 * NPOS + pos] = sqrtf(sc * ss);
        }
    }
}

extern "C" void kernel_launch(void* const* d_in, const int* in_sizes, int n_in,
                              void* d_out, int out_size, void* d_ws, size_t ws_size,
                              hipStream_t stream)
{
    const float* bbox   = (const float*)d_in[0];
    const float* center = (const float*)d_in[1];
    const float* cls    = (const float*)d_in[2];
    float* out = (float*)d_out;

    fcos_decode_kernel<<<BLOCKS_A + BLOCKS_B, 256, 0, stream>>>(bbox, center, cls, out);
}